// Round 16
// baseline (33694.794 us; speedup 1.0000x reference)
//
#include <hip/hip_runtime.h>

#define HIDDEN 256
#define TENC 336
#define HORIZ 168
#define BSZ 1024

typedef _Float16 f16;
typedef f16 f16x8 __attribute__((ext_vector_type(8)));
typedef float f32x4 __attribute__((ext_vector_type(4)));
typedef unsigned int u32;
typedef unsigned short u16;
typedef unsigned long long u64;

#define WMATF16 262144                 // f16 elems per converted matrix (512 KiB)
#define WS_TOTAL (6*WMATF16*2)         // 3 MiB

__device__ __forceinline__ float sigm(float x){ return 1.0f/(1.0f+__expf(-x)); }
__device__ __forceinline__ float tanh_f(float x){ return 2.0f/(1.0f+__expf(-2.0f*x)) - 1.0f; }

struct P {
  const float *x;
  const float *eWih0,*eWhh0,*eBih0,*eBhh0,*eWih1,*eWhh1,*eBih1,*eBhh1;
  const float *dWih0,*dWhh0,*dBih0,*dBhh0,*dWih1,*dWhh1,*dBih1,*dBhh1;
  const float *fcW,*fcB;
  float* out;
  char* ws;
};

struct WC {
  const float *s0,*s1,*s2,*s3,*s4,*s5;
  f16* dst;
};

// Convert 6 f32 weight matrices (1024x256) into MFMA-fragment-linear f16:
// slot s -> (m, n2 gate, dd dim16, kt kfrag, l lane); lane l holds
// W[n2*256 + dd*16 + (l&15)][kt*32 + 8*(l>>4) .. +7]   (R14/R15-verified frag)
__global__ void wconv(WC wc){
  int idx = blockIdx.x*blockDim.x + threadIdx.x;
  if (idx >= 6*32768) return;
  int m  = idx >> 15;
  int r  = idx & 32767;
  int l  = r & 63;
  int kt = (r>>6) & 7;
  int dd = (r>>9) & 15;
  int n2 = r >> 13;
  const float* S = (m==0)?wc.s0:(m==1)?wc.s1:(m==2)?wc.s2:(m==3)?wc.s3:(m==4)?wc.s4:wc.s5;
  const float* src = S + (n2*256 + dd*16 + (l&15))*256 + kt*32 + 8*(l>>4);
  float4 lo = *(const float4*)src;
  float4 hi = *(const float4*)(src+4);
  f16x8 v;
  v[0]=(f16)lo.x; v[1]=(f16)lo.y; v[2]=(f16)lo.z; v[3]=(f16)lo.w;
  v[4]=(f16)hi.x; v[5]=(f16)hi.y; v[6]=(f16)hi.z; v[7]=(f16)hi.w;
  *(f16x8*)(wc.dst + (size_t)idx*8) = v;
}

// one layer matmul pass: acc[n2*2+dh] += W(m-frag) * h(frag from LDS tile)
// h-tile LDS layout (fragment-linear): f16 index kt*512 + lane*8 holds
// h[row=lane&15][kt*32 + 8*(lane>>4) .. +7]
__device__ __forceinline__ void mmpass(f32x4* acc, const f16* wm, const f16* hsrc,
                                       int ddb, int lane){
  #pragma unroll
  for (int kt=0; kt<8; ++kt){
    f16x8 hf = *(const f16x8*)(hsrc + kt*512 + lane*8);
    #pragma unroll
    for (int n2=0; n2<4; ++n2){
      #pragma unroll
      for (int dh=0; dh<2; ++dh){
        f16x8 wfr = *(const f16x8*)(wm + (size_t)((((n2*16 + ddb + dh)*8) + kt)*64 + lane)*8);
        acc[n2*2+dh] = __builtin_amdgcn_mfma_f32_16x16x32_f16(wfr, hf, acc[n2*2+dh], 0,0,0);
      }
    }
  }
}

// transposed cell + direct LDS store. Thread owns batch row (lane&15) and
// 8 dims d = (w*2+dh)*16 + hq*4 + q with all 4 gates in acc[n2*2+dh][q].
__device__ __forceinline__ void cellstore(const f32x4* acc, const float* btab,
                                          const float* wxtab, float xr,
                                          float* cst, float* h8out,
                                          f16* hdst, int w, int row, int hq){
  #pragma unroll
  for (int dh=0; dh<2; ++dh){
    #pragma unroll
    for (int q=0; q<4; ++q){
      int d = (w*2+dh)*16 + hq*4 + q;
      int u = dh*4+q;
      float pi = acc[0+dh][q] + btab[      d] + xr*wxtab[      d];
      float pf = acc[2+dh][q] + btab[256 + d] + xr*wxtab[256 + d];
      float pg = acc[4+dh][q] + btab[512 + d] + xr*wxtab[512 + d];
      float po = acc[6+dh][q] + btab[768 + d] + xr*wxtab[768 + d];
      float ii = sigm(pi), ff = sigm(pf), gg = tanh_f(pg), oo = sigm(po);
      cst[u] = ff*cst[u] + ii*gg;
      h8out[u] = oo*tanh_f(cst[u]);
    }
    // pack 4 consecutive f16 and store into fragment-linear tile:
    // f16 idx = (d>>5)*512 + (((d>>3)&3)*16 + row)*8 + (d&7); kt=w, e=(hq&1)*4+q
    u64 v = 0;
    #pragma unroll
    for (int q=0; q<4; ++q){
      u16 b = __builtin_bit_cast(u16, (f16)h8out[dh*4+q]);
      v |= (u64)b << (16*q);
    }
    int o_ = 2*dh + (hq>>1);
    *(u64*)(hdst + w*512 + (o_*16 + row)*8 + (hq&1)*4) = v;
  }
}

__global__ __launch_bounds__(512) void lstm_main(P p){
  const int tid  = threadIdx.x;
  const int lane = tid & 63;
  const int w    = tid >> 6;        // wave 0..7, owns dims [w*32, w*32+32)
  const int row  = lane & 15;       // block-local batch row
  const int hq   = lane >> 4;       // dim quarter
  const int gRow = blockIdx.x*16 + row;
  const int ddb  = w*2;             // dim16-tile base

  __shared__ f16  hs0[2][4096];     // 16 rows x 256 dims, fragment-linear
  __shared__ f16  hs1[2][4096];
  __shared__ float xs[16*344];
  __shared__ float bias[3072];      // [0:1024) b0, [1024:2048) wx0, [2048:3072) b1
  __shared__ float pacc[2][16][8];  // pred partials per (parity, row, wave)

  const f16* wf = (const f16*)p.ws;

  // x tile -> LDS
  for (int i = tid; i < 16*TENC; i += 512){
    int rr = i / TENC, cc = i - rr*TENC;
    xs[rr*344 + cc] = p.x[(blockIdx.x*16 + rr)*TENC + cc];
  }
  // encoder bias tables -> LDS
  for (int i = tid; i < 1024; i += 512){
    bias[i]        = p.eBih0[i] + p.eBhh0[i];
    bias[1024 + i] = p.eWih0[i];
    bias[2048 + i] = p.eBih1[i] + p.eBhh1[i];
  }
  // zero the "previous" h buffers
  for (int i = tid; i < 4096; i += 512){
    hs0[1][i] = (f16)0.f; hs1[1][i] = (f16)0.f;
  }
  __syncthreads();

  float c0[8] = {0,0,0,0,0,0,0,0};
  float c1[8] = {0,0,0,0,0,0,0,0};
  int cur = 0;

  // ================= ENCODER (all block-local, 2 barriers/step) ============
  for (int r = 0; r < TENC; ++r){
    int prev = cur^1;
    // phase A: L0
    f32x4 acc[8] = {{0,0,0,0},{0,0,0,0},{0,0,0,0},{0,0,0,0},
                    {0,0,0,0},{0,0,0,0},{0,0,0,0},{0,0,0,0}};
    mmpass(acc, wf + 0*WMATF16, hs0[prev], ddb, lane);    // eWhh0 * h0(r-1)
    float h8[8];
    cellstore(acc, bias, bias+1024, xs[row*344 + r], c0, h8, hs0[cur], w, row, hq);
    __syncthreads();
    // phase B: L1
    f32x4 acc1[8] = {{0,0,0,0},{0,0,0,0},{0,0,0,0},{0,0,0,0},
                     {0,0,0,0},{0,0,0,0},{0,0,0,0},{0,0,0,0}};
    mmpass(acc1, wf + 1*WMATF16, hs0[cur],  ddb, lane);   // eWih1 * h0(r)
    mmpass(acc1, wf + 2*WMATF16, hs1[prev], ddb, lane);   // eWhh1 * h1(r-1)
    cellstore(acc1, bias+2048, bias+1024, 0.f, c1, h8, hs1[cur], w, row, hq);
    __syncthreads();
    cur ^= 1;
  }

  // ---- swap to decoder tables (last loop barrier already passed) ----
  for (int i = tid; i < 1024; i += 512){
    bias[i]        = p.dBih0[i] + p.dBhh0[i];
    bias[1024 + i] = p.dWih0[i];
    bias[2048 + i] = p.dBih1[i] + p.dBhh1[i];
  }
  float fcw[8];
  #pragma unroll
  for (int dh=0; dh<2; ++dh)
    #pragma unroll
    for (int q=0; q<4; ++q)
      fcw[dh*4+q] = p.fcW[(ddb+dh)*16 + hq*4 + q];
  float fcb = p.fcB[0];
  __syncthreads();

  // ================= DECODER ===============================================
  for (int t = 0; t < HORIZ; ++t){
    int prev = cur^1;
    // phase A: L0 with autoregressive input
    float inp;
    if (t == 0){
      inp = xs[row*344 + (TENC-1)];
    } else {
      float s_ = fcb;
      #pragma unroll
      for (int ww=0; ww<8; ++ww) s_ += pacc[(t-1)&1][row][ww];  // fixed order
      inp = s_;
    }
    f32x4 acc[8] = {{0,0,0,0},{0,0,0,0},{0,0,0,0},{0,0,0,0},
                    {0,0,0,0},{0,0,0,0},{0,0,0,0},{0,0,0,0}};
    mmpass(acc, wf + 3*WMATF16, hs0[prev], ddb, lane);    // dWhh0 * h0(t-1)
    float h8[8];
    cellstore(acc, bias, bias+1024, inp, c0, h8, hs0[cur], w, row, hq);
    if (t > 0 && w == 0 && lane < 16) p.out[gRow*HORIZ + (t-1)] = inp;
    __syncthreads();
    // phase B: L1 + pred partial
    f32x4 acc1[8] = {{0,0,0,0},{0,0,0,0},{0,0,0,0},{0,0,0,0},
                     {0,0,0,0},{0,0,0,0},{0,0,0,0},{0,0,0,0}};
    mmpass(acc1, wf + 4*WMATF16, hs0[cur],  ddb, lane);   // dWih1 * h0(t)
    mmpass(acc1, wf + 5*WMATF16, hs1[prev], ddb, lane);   // dWhh1 * h1(t-1)
    cellstore(acc1, bias+2048, bias+1024, 0.f, c1, h8, hs1[cur], w, row, hq);
    float s_ = 0.f;
    #pragma unroll
    for (int u=0; u<8; ++u) s_ += fcw[u]*h8[u];
    s_ += __shfl_xor(s_, 16); s_ += __shfl_xor(s_, 32);
    if (lane < 16) pacc[t&1][row][w] = s_;
    __syncthreads();
    cur ^= 1;
  }

  // final column: pred(167) from pacc parity 1
  {
    float s_ = fcb;
    #pragma unroll
    for (int ww=0; ww<8; ++ww) s_ += pacc[1][row][ww];
    if (w == 0 && lane < 16) p.out[gRow*HORIZ + (HORIZ-1)] = s_;
  }
}

extern "C" void kernel_launch(void* const* d_in, const int* in_sizes, int n_in,
                              void* d_out, int out_size, void* d_ws, size_t ws_size,
                              hipStream_t stream) {
  (void)in_sizes; (void)n_in; (void)out_size;
  if (ws_size < (size_t)WS_TOTAL) return;  // fail visibly (poisoned output)

  P prm;
  prm.x     = (const float*)d_in[0];
  prm.eWih0 = (const float*)d_in[1];  prm.eWhh0 = (const float*)d_in[2];
  prm.eBih0 = (const float*)d_in[3];  prm.eBhh0 = (const float*)d_in[4];
  prm.eWih1 = (const float*)d_in[5];  prm.eWhh1 = (const float*)d_in[6];
  prm.eBih1 = (const float*)d_in[7];  prm.eBhh1 = (const float*)d_in[8];
  prm.dWih0 = (const float*)d_in[9];  prm.dWhh0 = (const float*)d_in[10];
  prm.dBih0 = (const float*)d_in[11]; prm.dBhh0 = (const float*)d_in[12];
  prm.dWih1 = (const float*)d_in[13]; prm.dWhh1 = (const float*)d_in[14];
  prm.dBih1 = (const float*)d_in[15]; prm.dBhh1 = (const float*)d_in[16];
  prm.fcW   = (const float*)d_in[17]; prm.fcB   = (const float*)d_in[18];
  prm.out   = (float*)d_out;
  prm.ws    = (char*)d_ws;

  WC wc;
  wc.s0 = prm.eWhh0; wc.s1 = prm.eWih1; wc.s2 = prm.eWhh1;
  wc.s3 = prm.dWhh0; wc.s4 = prm.dWih1; wc.s5 = prm.dWhh1;
  wc.dst = (f16*)d_ws;

  hipLaunchKernelGGL(wconv, dim3(768), dim3(256), 0, stream, wc);
  hipLaunchKernelGGL(lstm_main, dim3(64), dim3(512), 0, stream, prm);
}

// Round 17
// 33620.663 us; speedup vs baseline: 1.0022x; 1.0022x over previous
//
#include <hip/hip_runtime.h>

#define HIDDEN 256
#define TENC 336
#define HORIZ 168
#define BSZ 1024

typedef _Float16 f16;
typedef f16 f16x8 __attribute__((ext_vector_type(8)));
typedef float f32x4 __attribute__((ext_vector_type(4)));
typedef unsigned int u32;
typedef unsigned short u16;
typedef unsigned long long u64;

#define WMATF16 262144                 // f16 elems per converted matrix (512 KiB)
#define WS_TOTAL (6*WMATF16*2)         // 3 MiB

__device__ __forceinline__ float sigm(float x){ return 1.0f/(1.0f+__expf(-x)); }
__device__ __forceinline__ float tanh_f(float x){ return 2.0f/(1.0f+__expf(-2.0f*x)) - 1.0f; }

struct P {
  const float *x;
  const float *eWih0,*eWhh0,*eBih0,*eBhh0,*eWih1,*eWhh1,*eBih1,*eBhh1;
  const float *dWih0,*dWhh0,*dBih0,*dBhh0,*dWih1,*dWhh1,*dBih1,*dBhh1;
  const float *fcW,*fcB;
  float* out;
  char* ws;
};

struct WC {
  const float *s0,*s1,*s2,*s3,*s4,*s5;
  f16* dst;
};

// Convert 6 f32 weight matrices (1024x256) into WAVE-CONTIGUOUS fragment
// layout: idx = m*32768 + w*4096 + i8*512 + kt*64 + l  (slots of 8 f16),
// where w = dim-tile pair (wave), i8 = n2*2+dh (gate/dim-sub), kt = K-frag.
// Lane l holds W[n2*256 + (w*2+dh)*16 + (l&15)][kt*32 + 8*(l>>4) .. +7]
// (R14/R15/R16-verified fragment mapping).
__global__ void wconv(WC wc){
  int idx = blockIdx.x*blockDim.x + threadIdx.x;
  if (idx >= 6*32768) return;
  int m  = idx >> 15;
  int r  = idx & 32767;
  int l  = r & 63;
  int kt = (r>>6) & 7;
  int i8 = (r>>9) & 7;
  int w  = (r>>12) & 7;
  int n2 = i8 >> 1, dh = i8 & 1;
  const float* S = (m==0)?wc.s0:(m==1)?wc.s1:(m==2)?wc.s2:(m==3)?wc.s3:(m==4)?wc.s4:wc.s5;
  const float* src = S + (n2*256 + (w*2+dh)*16 + (l&15))*256 + kt*32 + 8*(l>>4);
  float4 lo = *(const float4*)src;
  float4 hi = *(const float4*)(src+4);
  f16x8 v;
  v[0]=(f16)lo.x; v[1]=(f16)lo.y; v[2]=(f16)lo.z; v[3]=(f16)lo.w;
  v[4]=(f16)hi.x; v[5]=(f16)hi.y; v[6]=(f16)hi.z; v[7]=(f16)hi.w;
  *(f16x8*)(wc.dst + (size_t)idx*8) = v;
}

// software-pipelined layer pass: wmw = matrix base + w*32768 (wave chunk).
// frag(i,kt) at wmw + i*4096 + kt*512 + lane*8. Double-buffer by kt:
// load kt+1's 8 frags while MFMAing kt's. All indices compile-time.
__device__ __forceinline__ void mmpass(f32x4* acc, const f16* wmw, const f16* hsrc,
                                       int lane){
  f16x8 hf[8];
  #pragma unroll
  for (int kt=0; kt<8; ++kt)
    hf[kt] = *(const f16x8*)(hsrc + kt*512 + lane*8);
  const f16* b = wmw + lane*8;
  f16x8 wA[8], wB[8];
  #pragma unroll
  for (int i=0; i<8; ++i) wA[i] = *(const f16x8*)(b + i*4096 + 0*512);
  #pragma unroll
  for (int kt=0; kt<8; kt+=2){
    if (kt+1 < 8){
      #pragma unroll
      for (int i=0; i<8; ++i) wB[i] = *(const f16x8*)(b + i*4096 + (kt+1)*512);
    }
    #pragma unroll
    for (int i=0; i<8; ++i)
      acc[i] = __builtin_amdgcn_mfma_f32_16x16x32_f16(wA[i], hf[kt], acc[i], 0,0,0);
    if (kt+2 < 8){
      #pragma unroll
      for (int i=0; i<8; ++i) wA[i] = *(const f16x8*)(b + i*4096 + (kt+2)*512);
    }
    if (kt+1 < 8){
      #pragma unroll
      for (int i=0; i<8; ++i)
        acc[i] = __builtin_amdgcn_mfma_f32_16x16x32_f16(wB[i], hf[kt+1], acc[i], 0,0,0);
    }
  }
}

// transposed cell + direct LDS store (R16-verified mapping). Thread owns
// batch row (lane&15), 8 dims d = (w*2+dh)*16 + hq*4 + q, gates in acc[n2*2+dh].
__device__ __forceinline__ void cellstore(const f32x4* acc, const float* btab,
                                          const float* wxtab, float xr,
                                          float* cst, float* h8out,
                                          f16* hdst, int w, int row, int hq){
  #pragma unroll
  for (int dh=0; dh<2; ++dh){
    #pragma unroll
    for (int q=0; q<4; ++q){
      int d = (w*2+dh)*16 + hq*4 + q;
      int u = dh*4+q;
      float pi = acc[0+dh][q] + btab[      d] + xr*wxtab[      d];
      float pf = acc[2+dh][q] + btab[256 + d] + xr*wxtab[256 + d];
      float pg = acc[4+dh][q] + btab[512 + d] + xr*wxtab[512 + d];
      float po = acc[6+dh][q] + btab[768 + d] + xr*wxtab[768 + d];
      float ii = sigm(pi), ff = sigm(pf), gg = tanh_f(pg), oo = sigm(po);
      cst[u] = ff*cst[u] + ii*gg;
      h8out[u] = oo*tanh_f(cst[u]);
    }
    u64 v = 0;
    #pragma unroll
    for (int q=0; q<4; ++q){
      u16 b = __builtin_bit_cast(u16, (f16)h8out[dh*4+q]);
      v |= (u64)b << (16*q);
    }
    int o_ = 2*dh + (hq>>1);
    *(u64*)(hdst + w*512 + (o_*16 + row)*8 + (hq&1)*4) = v;
  }
}

__global__ __launch_bounds__(512, 2) void lstm_main(P p){
  const int tid  = threadIdx.x;
  const int lane = tid & 63;
  const int w    = tid >> 6;        // wave 0..7, owns dims [w*32, w*32+32)
  const int row  = lane & 15;       // block-local batch row
  const int hq   = lane >> 4;       // dim quarter
  const int gRow = blockIdx.x*16 + row;

  __shared__ f16  hs0[2][4096];     // 16 rows x 256 dims, fragment-linear
  __shared__ f16  hs1[2][4096];
  __shared__ float xs[16*344];
  __shared__ float bias[3072];      // [0:1024) b0, [1024:2048) wx0, [2048:3072) b1
  __shared__ float pacc[2][16][8];  // pred partials per (parity, row, wave)

  const f16* wf = (const f16*)p.ws;
  const int woff = w*32768;         // wave chunk offset within a matrix

  // x tile -> LDS
  for (int i = tid; i < 16*TENC; i += 512){
    int rr = i / TENC, cc = i - rr*TENC;
    xs[rr*344 + cc] = p.x[(blockIdx.x*16 + rr)*TENC + cc];
  }
  // encoder bias tables -> LDS
  for (int i = tid; i < 1024; i += 512){
    bias[i]        = p.eBih0[i] + p.eBhh0[i];
    bias[1024 + i] = p.eWih0[i];
    bias[2048 + i] = p.eBih1[i] + p.eBhh1[i];
  }
  // zero the "previous" h buffers
  for (int i = tid; i < 4096; i += 512){
    hs0[1][i] = (f16)0.f; hs1[1][i] = (f16)0.f;
  }
  __syncthreads();

  float c0[8] = {0,0,0,0,0,0,0,0};
  float c1[8] = {0,0,0,0,0,0,0,0};
  int cur = 0;

  // ================= ENCODER (block-local, 2 barriers/step) ================
  for (int r = 0; r < TENC; ++r){
    int prev = cur^1;
    // phase A: L0
    f32x4 acc[8] = {{0,0,0,0},{0,0,0,0},{0,0,0,0},{0,0,0,0},
                    {0,0,0,0},{0,0,0,0},{0,0,0,0},{0,0,0,0}};
    mmpass(acc, wf + 0*WMATF16 + woff, hs0[prev], lane);   // eWhh0 * h0(r-1)
    float h8[8];
    cellstore(acc, bias, bias+1024, xs[row*344 + r], c0, h8, hs0[cur], w, row, hq);
    __syncthreads();
    // phase B: L1
    f32x4 acc1[8] = {{0,0,0,0},{0,0,0,0},{0,0,0,0},{0,0,0,0},
                     {0,0,0,0},{0,0,0,0},{0,0,0,0},{0,0,0,0}};
    mmpass(acc1, wf + 1*WMATF16 + woff, hs0[cur],  lane);  // eWih1 * h0(r)
    mmpass(acc1, wf + 2*WMATF16 + woff, hs1[prev], lane);  // eWhh1 * h1(r-1)
    cellstore(acc1, bias+2048, bias+1024, 0.f, c1, h8, hs1[cur], w, row, hq);
    __syncthreads();
    cur ^= 1;
  }

  // ---- swap to decoder tables ----
  for (int i = tid; i < 1024; i += 512){
    bias[i]        = p.dBih0[i] + p.dBhh0[i];
    bias[1024 + i] = p.dWih0[i];
    bias[2048 + i] = p.dBih1[i] + p.dBhh1[i];
  }
  float fcw[8];
  #pragma unroll
  for (int dh=0; dh<2; ++dh)
    #pragma unroll
    for (int q=0; q<4; ++q)
      fcw[dh*4+q] = p.fcW[(w*2+dh)*16 + hq*4 + q];
  float fcb = p.fcB[0];
  __syncthreads();

  // ================= DECODER ===============================================
  for (int t = 0; t < HORIZ; ++t){
    int prev = cur^1;
    // phase A: L0 with autoregressive input
    float inp;
    if (t == 0){
      inp = xs[row*344 + (TENC-1)];
    } else {
      float s_ = fcb;
      #pragma unroll
      for (int ww=0; ww<8; ++ww) s_ += pacc[(t-1)&1][row][ww];  // fixed order
      inp = s_;
    }
    f32x4 acc[8] = {{0,0,0,0},{0,0,0,0},{0,0,0,0},{0,0,0,0},
                    {0,0,0,0},{0,0,0,0},{0,0,0,0},{0,0,0,0}};
    mmpass(acc, wf + 3*WMATF16 + woff, hs0[prev], lane);   // dWhh0 * h0(t-1)
    float h8[8];
    cellstore(acc, bias, bias+1024, inp, c0, h8, hs0[cur], w, row, hq);
    if (t > 0 && w == 0 && lane < 16) p.out[gRow*HORIZ + (t-1)] = inp;
    __syncthreads();
    // phase B: L1 + pred partial
    f32x4 acc1[8] = {{0,0,0,0},{0,0,0,0},{0,0,0,0},{0,0,0,0},
                     {0,0,0,0},{0,0,0,0},{0,0,0,0},{0,0,0,0}};
    mmpass(acc1, wf + 4*WMATF16 + woff, hs0[cur],  lane);  // dWih1 * h0(t)
    mmpass(acc1, wf + 5*WMATF16 + woff, hs1[prev], lane);  // dWhh1 * h1(t-1)
    cellstore(acc1, bias+2048, bias+1024, 0.f, c1, h8, hs1[cur], w, row, hq);
    float s_ = 0.f;
    #pragma unroll
    for (int u=0; u<8; ++u) s_ += fcw[u]*h8[u];
    s_ += __shfl_xor(s_, 16); s_ += __shfl_xor(s_, 32);
    if (lane < 16) pacc[t&1][row][w] = s_;
    __syncthreads();
    cur ^= 1;
  }

  // final column: pred(167)
  {
    float s_ = fcb;
    #pragma unroll
    for (int ww=0; ww<8; ++ww) s_ += pacc[1][row][ww];
    if (w == 0 && lane < 16) p.out[gRow*HORIZ + (HORIZ-1)] = s_;
  }
}

extern "C" void kernel_launch(void* const* d_in, const int* in_sizes, int n_in,
                              void* d_out, int out_size, void* d_ws, size_t ws_size,
                              hipStream_t stream) {
  (void)in_sizes; (void)n_in; (void)out_size;
  if (ws_size < (size_t)WS_TOTAL) return;  // fail visibly (poisoned output)

  P prm;
  prm.x     = (const float*)d_in[0];
  prm.eWih0 = (const float*)d_in[1];  prm.eWhh0 = (const float*)d_in[2];
  prm.eBih0 = (const float*)d_in[3];  prm.eBhh0 = (const float*)d_in[4];
  prm.eWih1 = (const float*)d_in[5];  prm.eWhh1 = (const float*)d_in[6];
  prm.eBih1 = (const float*)d_in[7];  prm.eBhh1 = (const float*)d_in[8];
  prm.dWih0 = (const float*)d_in[9];  prm.dWhh0 = (const float*)d_in[10];
  prm.dBih0 = (const float*)d_in[11]; prm.dBhh0 = (const float*)d_in[12];
  prm.dWih1 = (const float*)d_in[13]; prm.dWhh1 = (const float*)d_in[14];
  prm.dBih1 = (const float*)d_in[15]; prm.dBhh1 = (const float*)d_in[16];
  prm.fcW   = (const float*)d_in[17]; prm.fcB   = (const float*)d_in[18];
  prm.out   = (float*)d_out;
  prm.ws    = (char*)d_ws;

  WC wc;
  wc.s0 = prm.eWhh0; wc.s1 = prm.eWih1; wc.s2 = prm.eWhh1;
  wc.s3 = prm.dWhh0; wc.s4 = prm.dWih1; wc.s5 = prm.dWhh1;
  wc.dst = (f16*)d_ws;

  hipLaunchKernelGGL(wconv, dim3(768), dim3(256), 0, stream, wc);
  hipLaunchKernelGGL(lstm_main, dim3(64), dim3(512), 0, stream, prm);
}